// Round 5
// baseline (108.189 us; speedup 1.0000x reference)
//
#include <hip/hip_runtime.h>
#include <hip/hip_cooperative_groups.h>
#include <math.h>

namespace cg = cooperative_groups;

#define BB 128   // batch
#define VV 4     // views
#define NN 512   // BB*VV rows
#define DD 128   // feature dim
#define NT 256   // threads per block
#define NBLK 256 // blocks; 2 anchors per block -> halves the row-sweep traffic

// ---------------------------------------------------------------------------
// Single cooperative kernel. Block b handles anchors a0=b and a1=b+256.
// Phase 1: one fused sweep over all 512 rows computes ss_j = <row_j,row_j>
//          and dot_j vs BOTH anchors (8 lanes/row, 4 float4 loads/lane,
//          butterfly reduce) -> one 256 KB read pass serves two anchors.
// Phase 2 (x2 anchors): distances d_j = sqrt(max(sn_a + sn_j - 2*dot*inv_a*
//          inv_j, 0)) (== reference normalize-then-dot to ~1e-7; absmax 0.0
//          in rounds 2-4), ballot compaction into pos/neg lists, relu pair
//          loop accumulating thread-local sum/count across both anchors.
// Phase 3: block reduce -> psum[b], pcnt[b]; grid.sync(); block 0 reduces
//          256 partials and writes out = C>0 ? S/C : 0.
// Deterministic; no global atomics; ws needs no init (write-before-read).
// ---------------------------------------------------------------------------
__global__ __launch_bounds__(NT)
void fused_all(const float* __restrict__ feat,
               const int* __restrict__ labels,
               float* __restrict__ psum,
               float* __restrict__ pcnt,
               float* __restrict__ out) {
    __shared__ float s_ss[NN];
    __shared__ float s_dot[2][NN];
    __shared__ float s_pos[NN];
    __shared__ float s_neg[NN];
    __shared__ int   s_lab[BB];
    __shared__ int   s_np, s_nn;
    __shared__ float s_wsum[NT / 64];
    __shared__ unsigned int s_wcnt[NT / 64];

    const int bid  = blockIdx.x;
    const int tid  = threadIdx.x;
    const int wave = tid >> 6;      // 0..3
    const int lane = tid & 63;
    const int grp  = lane >> 3;     // 8 row-groups of 8 lanes
    const int l8   = lane & 7;

    if (tid < BB) s_lab[tid] = labels[tid];

    // anchor fragments for both anchors (lane's 4 float4s each)
    const int a0 = bid, a1 = bid + NBLK;
    const float4* ar0 = (const float4*)(feat + (size_t)(a0 & (BB - 1)) * (VV * DD) + (a0 >> 7) * DD);
    const float4* ar1 = (const float4*)(feat + (size_t)(a1 & (BB - 1)) * (VV * DD) + (a1 >> 7) * DD);
    float4 af[4], bf[4];
    #pragma unroll
    for (int k = 0; k < 4; ++k) { af[k] = ar0[l8 + 8 * k]; bf[k] = ar1[l8 + 8 * k]; }

    // Phase 1: fused ss + dual-dot sweep; wave w covers rows [w*128, w*128+128)
    #pragma unroll 4
    for (int it = 0; it < 16; ++it) {
        const int j  = (wave << 7) + (it << 3) + grp;
        const int jb = j & (BB - 1), jv = j >> 7;
        const float4* jr = (const float4*)(feat + (size_t)jb * (VV * DD) + jv * DD);
        float ss = 0.f, d0 = 0.f, d1 = 0.f;
        #pragma unroll
        for (int k = 0; k < 4; ++k) {
            float4 x = jr[l8 + 8 * k];
            ss = fmaf(x.x, x.x,     fmaf(x.y, x.y,     fmaf(x.z, x.z,     fmaf(x.w, x.w,     ss))));
            d0 = fmaf(x.x, af[k].x, fmaf(x.y, af[k].y, fmaf(x.z, af[k].z, fmaf(x.w, af[k].w, d0))));
            d1 = fmaf(x.x, bf[k].x, fmaf(x.y, bf[k].y, fmaf(x.z, bf[k].z, fmaf(x.w, bf[k].w, d1))));
        }
        #pragma unroll
        for (int off = 4; off > 0; off >>= 1) {
            ss += __shfl_xor(ss, off);
            d0 += __shfl_xor(d0, off);
            d1 += __shfl_xor(d1, off);
        }
        if (l8 == 0) { s_ss[j] = ss; s_dot[0][j] = d0; s_dot[1][j] = d1; }
    }
    __syncthreads();

    // Phase 2: per-anchor distances -> compaction -> pair loop
    float lsum = 0.f;
    unsigned int lcnt = 0;
    #pragma unroll
    for (int h = 0; h < 2; ++h) {
        if (h) __syncthreads();            // protect s_np/s_pos/s_neg reuse
        const int a = bid + (h << 8);
        if (tid == 0) { s_np = 0; s_nn = 0; }

        const float ssa  = s_ss[a];
        const float inva = 1.f / fmaxf(sqrtf(ssa), 1e-12f);
        const float sna  = ssa * inva * inva;
        float dreg[2];
        #pragma unroll
        for (int rnd = 0; rnd < 2; ++rnd) {
            const int j = tid + (rnd << 8);
            float ssj  = s_ss[j];
            float invj = 1.f / fmaxf(sqrtf(ssj), 1e-12f);
            float snj  = ssj * invj * invj;
            float dot  = s_dot[h][j] * inva * invj;
            float sq   = fmaxf(sna + snj - 2.f * dot, 0.f);
            dreg[rnd]  = (sq > 0.f) ? sqrtf(sq) : 0.f;   // safe_sqrt semantics
        }
        __syncthreads();                   // s_np reset visible

        const int la = s_lab[a & (BB - 1)];
        #pragma unroll
        for (int rnd = 0; rnd < 2; ++rnd) {
            const int j = tid + (rnd << 8);
            bool same  = (s_lab[j & (BB - 1)] == la);
            bool ispos = same & (j != a);
            bool isneg = !same;
            unsigned long long mp = __ballot(ispos);
            unsigned long long mn = __ballot(isneg);
            int basep = 0, basen = 0;
            if (lane == 0) {
                basep = atomicAdd(&s_np, (int)__popcll(mp));
                basen = atomicAdd(&s_nn, (int)__popcll(mn));
            }
            basep = __shfl(basep, 0);
            basen = __shfl(basen, 0);
            unsigned long long below = (1ull << lane) - 1ull;
            if (ispos) s_pos[basep + (int)__popcll(mp & below)] = dreg[rnd];
            if (isneg) s_neg[basen + (int)__popcll(mn & below)] = dreg[rnd];
        }
        __syncthreads();

        const int np = s_np, nneg = s_nn;
        for (int p = 0; p < np; ++p) {
            float dp = s_pos[p];           // LDS broadcast
            for (int n = tid; n < nneg; n += NT) {
                float diff = dp - s_neg[n];
                if (diff > 0.f) { lsum += diff; lcnt++; }
            }
        }
    }

    // Phase 3: block reduce -> partials
    #pragma unroll
    for (int off = 32; off > 0; off >>= 1) {
        lsum += __shfl_down(lsum, off);
        lcnt += __shfl_down(lcnt, off);
    }
    if (lane == 0) { s_wsum[wave] = lsum; s_wcnt[wave] = lcnt; }
    __syncthreads();
    if (tid == 0) {
        psum[bid] = s_wsum[0] + s_wsum[1] + s_wsum[2] + s_wsum[3];
        pcnt[bid] = (float)(s_wcnt[0] + s_wcnt[1] + s_wcnt[2] + s_wcnt[3]);
    }

    // grid-wide barrier, then block 0 finalizes
    cg::this_grid().sync();

    if (bid == 0) {
        float s = psum[tid];
        float c = pcnt[tid];
        #pragma unroll
        for (int off = 32; off > 0; off >>= 1) {
            s += __shfl_down(s, off);
            c += __shfl_down(c, off);
        }
        if (lane == 0) { s_wsum[wave] = s; s_wcnt[wave] = (unsigned int)c; }
        __syncthreads();
        if (tid == 0) {
            float S = s_wsum[0] + s_wsum[1] + s_wsum[2] + s_wsum[3];
            float C = (float)(s_wcnt[0] + s_wcnt[1] + s_wcnt[2] + s_wcnt[3]);
            out[0] = (C > 0.f) ? S / C : 0.f;
        }
    }
}

extern "C" void kernel_launch(void* const* d_in, const int* in_sizes, int n_in,
                              void* d_out, int out_size, void* d_ws, size_t ws_size,
                              hipStream_t stream) {
    const float* feat   = (const float*)d_in[0];   // [128, 4, 128] fp32
    const int*   labels = (const int*)d_in[1];     // [128] int32
    float* out = (float*)d_out;

    float* psum = (float*)d_ws;          // NBLK floats
    float* pcnt = psum + NBLK;           // NBLK floats

    void* args[] = { (void*)&feat, (void*)&labels, (void*)&psum,
                     (void*)&pcnt, (void*)&out };
    hipLaunchCooperativeKernel((void*)fused_all, dim3(NBLK), dim3(NT),
                               args, 0, stream);
}